// Round 8
// baseline (148.923 us; speedup 1.0000x reference)
//
#include <hip/hip_runtime.h>

// Conv2d 3x3 s1 p1 NCHW fp32: N=32, Cin=128, H=W=56, Cout=256.
// Round 8: R7 + (a) ph4 barrier merge -> 4 barriers/tile; (b) vectorized
//   LDS-transpose epilogue (reuse As 64KB, XOR-swizzled <=2-way, bias fused,
//   dwordx4 stores 1KB-contiguous).
//   Hazard distances (re-derived): every STAGE region's last LDS read is
//   >=2 barriers (~2800cy) before the write lands; read-queue depth ~1150cy.
//   vmcnt(4) at ph4 drains tile t+1 fully before next ph1 reads; 2 halves fly.

typedef __attribute__((ext_vector_type(8))) short short8;
typedef __attribute__((ext_vector_type(4))) float float4v;

constexpr int NB = 32, CI = 128, HH = 56, WW = 56, CO = 256;
constexpr int HWP = HH * WW;                 // 3136
constexpr int HP = 58, WP = 58;              // padded spatial dims
constexpr size_t XTP_BYTES = (size_t)NB * HP * WP * CI * 2;   // 27,553,792
constexpr size_t WT_OFF    = XTP_BYTES;
constexpr size_t WT_BYTES  = (size_t)9 * CO * CI * 2;         // 589,824
constexpr size_t WS_NEED   = WT_OFF + WT_BYTES;

__device__ inline ushort f2bf(float v) {
    union { float f; uint u; } c; c.f = v;
    uint u = c.u;
    return (ushort)((u + 0x7fffu + ((u >> 16) & 1u)) >> 16);
}

__device__ inline void gll(const ushort* g, ushort* l) {
    __builtin_amdgcn_global_load_lds(
        (const __attribute__((address_space(1))) uint*)g,
        (__attribute__((address_space(3))) uint*)l, 16, 0, 0);
}

#define BAR() do { asm volatile("" ::: "memory"); \
                   __builtin_amdgcn_s_barrier(); \
                   asm volatile("" ::: "memory"); } while (0)

// ---- x: [n][ci][h][w] f32 -> xTp interior: [n][h+1][w+1][ci] bf16 ----
__global__ __launch_bounds__(256) void xform_x(const float* __restrict__ x,
                                               ushort* __restrict__ xTp) {
    int b = blockIdx.x;
    int cit = b & 3;
    int hwt = (b >> 2) % 49;
    int n   = b / (4 * 49);
    int ci0 = cit * 32, hw0 = hwt * 64;
    __shared__ float t[32][65];
    int tx = threadIdx.x;
    int col = tx & 63, r4 = tx >> 6;
#pragma unroll
    for (int rr = 0; rr < 8; ++rr) {
        int row = rr * 4 + r4;
        t[row][col] = x[((size_t)n * CI + ci0 + row) * HWP + hw0 + col];
    }
    __syncthreads();
    int i = tx & 31, j0 = tx >> 5;
#pragma unroll
    for (int jj = 0; jj < 8; ++jj) {
        int j = jj * 8 + j0;
        int hw = hw0 + j;
        int h = hw / WW, w = hw % WW;
        xTp[(((size_t)n * HP + h + 1) * WP + (w + 1)) * CI + ci0 + i] = f2bf(t[i][j]);
    }
}

// ---- zero-fill padded borders ----
__global__ __launch_bounds__(256) void xform_border(ushort* __restrict__ xTp) {
    int u = blockIdx.x * 256 + threadIdx.x;   // 116736 units of short8
    int ci8 = u & 15;
    int r = u >> 4;
    int n = r / 228, bb = r % 228;
    int hp, wp;
    if (bb < 58)       { hp = 0;  wp = bb; }
    else if (bb < 116) { hp = 57; wp = bb - 58; }
    else { int c = bb - 116; hp = 1 + (c >> 1); wp = (c & 1) * 57; }
    short8 z = (short8)0;
    *reinterpret_cast<short8*>(xTp + (((size_t)n * HP + hp) * WP + wp) * CI + ci8 * 8) = z;
}

// ---- w: [co][ci][kh][kw] f32 -> wT: [tap][co][ci] bf16 ----
__global__ __launch_bounds__(256) void xform_w(const float* __restrict__ w,
                                               ushort* __restrict__ wT) {
    int o = blockIdx.x * 256 + threadIdx.x;
    int ci = o & 127;
    int co = (o >> 7) & 255;
    int tap = o >> 15;
    wT[o] = f2bf(w[((size_t)co * CI + ci) * 9 + tap]);
}

// ---- main implicit GEMM: 256x256, 4-phase/tile, 4 barriers/tile ----
__global__ __launch_bounds__(512, 2) void gemm_conv(
    const ushort* __restrict__ xTp, const ushort* __restrict__ wT,
    const float* __restrict__ bias, float* __restrict__ out)
{
    __shared__ ushort As[2][256 * 64];   // 32KB x2 (weights: co x k)
    __shared__ ushort Bs[2][256 * 64];   // 32KB x2 (im2col : m  x k)

    // XCD swizzle: 392 = 8 x 49, bijective
    int b = blockIdx.x;
    const int mblk = (b & 7) * 49 + (b >> 3);

    const int tid = threadIdx.x, lane = tid & 63, wv = tid >> 6;  // 8 waves
    const int wr = wv >> 2;          // co-half  (0..1) -> 128 co rows
    const int wc = wv & 3;           // m-quarter(0..3) -> 64 m cols

    // staging addressing (half-tile = 128 rows x 64 k = 16KB; 2 loads/thr)
    const int s8 = (((tid & 7) ^ ((tid >> 3) & 7))) * 8;   // src chunk elems
    const int aSrc = (tid >> 3) * CI + s8;
    const int dstOff = (tid >> 3) * 64 + (tid & 7) * 8;

    int bPix[4];  // [h*2+q]: pixel base offset incl. s8
#pragma unroll
    for (int hq = 0; hq < 4; ++hq) {
        int m = mblk * 256 + (hq >> 1) * 128 + (hq & 1) * 64 + (tid >> 3);
        int n = m / HWP, hw = m % HWP, h = hw / WW, w = hw % WW;
        bPix[hq] = ((n * HP + h + 1) * WP + (w + 1)) * CI + s8;
    }

    // fragment-read addressing
    const int ck0 = (((lane >> 4)) ^ (lane & 7)) * 8;
    const int ck1 = ((4 + (lane >> 4)) ^ (lane & 7)) * 8;
    const int aRowOff = (wr * 128 + (lane & 15)) * 64;
    const int bRowOff = (wc * 64 + (lane & 15)) * 64;

    float4v acc[8][4];
#pragma unroll
    for (int i = 0; i < 8; ++i)
#pragma unroll
        for (int j = 0; j < 4; ++j) acc[i][j] = (float4v)(0.0f);

    short8 aF[4][2];
    short8 bQ0[2][2];
    short8 bQ1[2][2];

    auto STAGE_A = [&](int buf, int t, int h) {
        int tap = t >> 1, kh = (t & 1) * 64;
        const ushort* src = wT + aSrc + tap * (CO * CI) + kh + h * 16384;
        ushort* dst = &As[buf][h * 8192 + dstOff];
        gll(src, dst);
        gll(src + 8192, dst + 4096);
    };
    auto STAGE_B = [&](int buf, int t, int h) {
        int tap = t >> 1, kh = (t & 1) * 64;
        int dh = tap / 3 - 1, dw = tap % 3 - 1;
        int toff = (dh * WP + dw) * CI + kh;
        ushort* dst = &Bs[buf][h * 8192 + dstOff];
        gll(xTp + bPix[h * 2 + 0] + toff, dst);
        gll(xTp + bPix[h * 2 + 1] + toff, dst + 4096);
    };
    auto LDA = [&](int buf, int qr) {
        const ushort* p = &As[buf][aRowOff + qr * 4096];
#pragma unroll
        for (int fi = 0; fi < 4; ++fi) {
            aF[fi][0] = *(const short8*)(p + fi * 1024 + ck0);
            aF[fi][1] = *(const short8*)(p + fi * 1024 + ck1);
        }
    };
    auto LDB = [&](int buf, int qc, short8 (&bF)[2][2]) {
        const ushort* p = &Bs[buf][bRowOff + qc * 2048];
#pragma unroll
        for (int gi = 0; gi < 2; ++gi) {
            bF[gi][0] = *(const short8*)(p + gi * 1024 + ck0);
            bF[gi][1] = *(const short8*)(p + gi * 1024 + ck1);
        }
    };

// kc-OUTER: two runs of 8 independent MFMAs
#define MMQ(QR, QC, BF) do { \
    __builtin_amdgcn_s_setprio(1); \
    _Pragma("unroll") \
    for (int kc = 0; kc < 2; ++kc) \
        _Pragma("unroll") \
        for (int fi = 0; fi < 4; ++fi) \
            _Pragma("unroll") \
            for (int gi = 0; gi < 2; ++gi) \
                acc[(QR)*4+fi][(QC)*2+gi] = __builtin_amdgcn_mfma_f32_16x16x32_bf16( \
                    aF[fi][kc], (BF)[gi][kc], acc[(QR)*4+fi][(QC)*2+gi], 0, 0, 0); \
    __builtin_amdgcn_s_setprio(0); \
} while (0)

    // One K-tile, 4 phases, 4 barriers (ph4's two merged into one).
    auto TILE = [&](int c, int t) {
        // ph1: read A-qr0 + B-qc0 ; stage A-h1(t+1) -> buf c^1
        LDA(c, 0);
        LDB(c, 0, bQ0);
        if (t + 1 < 18) STAGE_A(c ^ 1, t + 1, 1);
        BAR();
        MMQ(0, 0, bQ0);
        // ph2: read B-qc1 ; stage B-h1(t+1) -> buf c^1
        LDB(c, 1, bQ1);
        if (t + 1 < 18) STAGE_B(c ^ 1, t + 1, 1);
        BAR();
        MMQ(0, 1, bQ1);
        // ph3: read A-qr1 ; stage B-h0(t+2) -> buf c
        LDA(c, 1);
        if (t + 2 < 18) STAGE_B(c, t + 2, 0);
        BAR();
        MMQ(1, 1, bQ1);
        // ph4 (merged): stage A-h0(t+2); counted drain; ONE barrier; MFMA
        if (t + 2 < 18) STAGE_A(c, t + 2, 0);
        if (t <= 15)      { asm volatile("s_waitcnt vmcnt(4)" ::: "memory"); }
        else if (t == 16) { asm volatile("s_waitcnt vmcnt(0)" ::: "memory"); }
        BAR();
        MMQ(1, 0, bQ0);
    };

    // prologue: tile0 (4 halves) + B-h0(1), A-h0(1)
    STAGE_A(0, 0, 0); STAGE_A(0, 0, 1);
    STAGE_B(0, 0, 0); STAGE_B(0, 0, 1);
    STAGE_B(1, 1, 0); STAGE_A(1, 1, 0);
    asm volatile("s_waitcnt vmcnt(4)" ::: "memory");
    BAR();

#pragma unroll 1
    for (int tp = 0; tp < 18; tp += 2) {   // 9 pairs, static parity
        TILE(0, tp);
        TILE(1, tp + 1);
    }
#undef MMQ

    // ---- vectorized epilogue via LDS transpose (reuse As = 64KB f32 buf) ----
    // Per pass q (co-quarter [64q,64q+64)): writer waves (wr==q>>1) scatter
    // acc+bias into lbuf[64][256] with XOR swizzle swz(c)=((c^(c>>2))&3)<<3
    // (write: 4 lane-groups get distinct swz -> <=2-way; read: <=2-way).
    // Readers: all threads store dwordx4, 1KB contiguous per instruction.
    const int m0  = mblk * 256;
    float bv[8][4];
#pragma unroll
    for (int f = 0; f < 8; ++f)
#pragma unroll
        for (int r = 0; r < 4; ++r)
            bv[f][r] = bias[wr * 128 + f * 16 + (lane >> 4) * 4 + r];

    float* lbuf = (float*)&As[0][0];   // 16384 floats = 64KB
    const int rd_col = tid >> 3;                   // 0..63 (co within quarter)
    const int rd_swz = ((rd_col ^ (rd_col >> 2)) & 3) << 3;

#pragma unroll 1
    for (int q = 0; q < 4; ++q) {
        BAR();   // previous pass's reads (or K-loop) complete
        if (wr == (q >> 1)) {
            const int fb = 4 * (q & 1);
#pragma unroll
            for (int f4 = 0; f4 < 4; ++f4) {
#pragma unroll
                for (int r = 0; r < 4; ++r) {
                    int co_l = f4 * 16 + (lane >> 4) * 4 + r;   // 0..63
                    int swz = ((co_l ^ (co_l >> 2)) & 3) << 3;
#pragma unroll
                    for (int g = 0; g < 4; ++g) {
                        int ml = wc * 64 + g * 16 + (lane & 15);
                        lbuf[co_l * 256 + (ml ^ swz)] = acc[fb + f4][g][r] + bv[fb + f4][r];
                    }
                }
            }
        }
        BAR();
        const int co = q * 64 + rd_col;
#pragma unroll
        for (int k = 0; k < 8; ++k) {
            int ml = ((tid & 7) + 8 * k) * 4;       // 4-float chunk, 4-aligned
            float4v v = *(const float4v*)&lbuf[rd_col * 256 + (ml ^ rd_swz)];
            int m = m0 + ml;
            int n = m / HWP, hw = m % HWP;          // HWP%4==0 -> no straddle
            *(float4v*)(out + ((size_t)n * CO + co) * HWP + hw) = v;
        }
    }
}

// ---- fallback (round-1 direct conv) if ws too small ----
__global__ __launch_bounds__(256) void conv_k(
    const float* __restrict__ x, const float* __restrict__ wgt,
    const float* __restrict__ bias, float* __restrict__ out)
{
    int idx = blockIdx.x * 256 + threadIdx.x;
    int wg = idx % 14; int t = idx / 14;
    int ho = t % 56; t /= 56;
    int cog = t % 64; int n = t / 64;
    int w0 = wg * 4, co0 = cog * 4;
    float acc[4][4];
#pragma unroll
    for (int j = 0; j < 4; ++j) {
        float bj = bias[co0 + j];
#pragma unroll
        for (int p = 0; p < 4; ++p) acc[j][p] = bj;
    }
    const float* xn = x + (size_t)n * CI * HWP;
    for (int ci = 0; ci < CI; ++ci) {
        float xr[3][6];
#pragma unroll
        for (int kh = 0; kh < 3; ++kh) {
            int hi = ho + kh - 1;
            if (hi >= 0 && hi < HH) {
                const float* row = xn + ((size_t)ci * HH + hi) * WW;
                float4 cc = *reinterpret_cast<const float4*>(row + w0);
                xr[kh][1] = cc.x; xr[kh][2] = cc.y; xr[kh][3] = cc.z; xr[kh][4] = cc.w;
                xr[kh][0] = (w0 > 0) ? row[w0 - 1] : 0.0f;
                xr[kh][5] = (w0 + 4 < WW) ? row[w0 + 4] : 0.0f;
            } else {
#pragma unroll
                for (int q = 0; q < 6; ++q) xr[kh][q] = 0.0f;
            }
        }
#pragma unroll
        for (int j = 0; j < 4; ++j) {
            const float* wp = wgt + ((size_t)(co0 + j) * CI + ci) * 9;
            float wvv[9];
#pragma unroll
            for (int q = 0; q < 9; ++q) wvv[q] = wp[q];
#pragma unroll
            for (int kh = 0; kh < 3; ++kh)
#pragma unroll
                for (int kw = 0; kw < 3; ++kw)
#pragma unroll
                    for (int p = 0; p < 4; ++p)
                        acc[j][p] = fmaf(xr[kh][p + kw], wvv[kh * 3 + kw], acc[j][p]);
        }
    }
#pragma unroll
    for (int j = 0; j < 4; ++j) {
        float4 v = make_float4(acc[j][0], acc[j][1], acc[j][2], acc[j][3]);
        *reinterpret_cast<float4*>(out + (((size_t)n * CO + co0 + j) * HH + ho) * WW + w0) = v;
    }
}

extern "C" void kernel_launch(void* const* d_in, const int* in_sizes, int n_in,
                              void* d_out, int out_size, void* d_ws, size_t ws_size,
                              hipStream_t stream) {
    const float* x = (const float*)d_in[0];
    const float* w = (const float*)d_in[1];
    const float* b = (const float*)d_in[2];
    float* out = (float*)d_out;

    if (ws_size < WS_NEED) {  // safety fallback
        hipLaunchKernelGGL(conv_k, dim3(6272), dim3(256), 0, stream, x, w, b, out);
        return;
    }

    ushort* xTp = (ushort*)d_ws;
    ushort* wT  = (ushort*)((char*)d_ws + WT_OFF);

    hipLaunchKernelGGL(xform_x, dim3(32 * 49 * 4), dim3(256), 0, stream, x, xTp);
    hipLaunchKernelGGL(xform_border, dim3(456), dim3(256), 0, stream, xTp);
    hipLaunchKernelGGL(xform_w, dim3(9 * CO * CI / 256), dim3(256), 0, stream, w, wT);
    hipLaunchKernelGGL(gemm_conv, dim3(392), dim3(512), 0, stream,
                       xTp, wT, b, out);
}

// Round 9
// 104.564 us; speedup vs baseline: 1.4242x; 1.4242x over previous
//
#include <hip/hip_runtime.h>

// Conv2d 3x3 s1 p1 NCHW fp32: N=32, Cin=128, H=W=56, Cout=256.
// Round 9: 256x256/BK=64 implicit GEMM, ONE barrier per K-tile.
//   Per tile t (buf c=t&1): stage all 8 gll for t+1 -> c^1; fragment reads
//   software-pipelined in source order (LDB1 before MMQs; LDA1 after
//   MMQ(0,1) issue); compiler emits exact per-register lgkm waits;
//   vmcnt(0)+BAR at tile boundary (loads 1 full tile in flight -> ~free,
//   barrier makes the guarantee collective). Epilogue = R7 scalar form
//   (R8's vector epilogue caused 3.25x HBM write amplification - reverted).

typedef __attribute__((ext_vector_type(8))) short short8;
typedef __attribute__((ext_vector_type(4))) float float4v;

constexpr int NB = 32, CI = 128, HH = 56, WW = 56, CO = 256;
constexpr int HWP = HH * WW;                 // 3136
constexpr int HP = 58, WP = 58;              // padded spatial dims
constexpr size_t XTP_BYTES = (size_t)NB * HP * WP * CI * 2;   // 27,553,792
constexpr size_t WT_OFF    = XTP_BYTES;
constexpr size_t WT_BYTES  = (size_t)9 * CO * CI * 2;         // 589,824
constexpr size_t WS_NEED   = WT_OFF + WT_BYTES;

__device__ inline ushort f2bf(float v) {
    union { float f; uint u; } c; c.f = v;
    uint u = c.u;
    return (ushort)((u + 0x7fffu + ((u >> 16) & 1u)) >> 16);
}

__device__ inline void gll(const ushort* g, ushort* l) {
    __builtin_amdgcn_global_load_lds(
        (const __attribute__((address_space(1))) uint*)g,
        (__attribute__((address_space(3))) uint*)l, 16, 0, 0);
}

#define BAR() do { asm volatile("" ::: "memory"); \
                   __builtin_amdgcn_s_barrier(); \
                   asm volatile("" ::: "memory"); } while (0)

// ---- x: [n][ci][h][w] f32 -> xTp interior: [n][h+1][w+1][ci] bf16 ----
__global__ __launch_bounds__(256) void xform_x(const float* __restrict__ x,
                                               ushort* __restrict__ xTp) {
    int b = blockIdx.x;
    int cit = b & 3;
    int hwt = (b >> 2) % 49;
    int n   = b / (4 * 49);
    int ci0 = cit * 32, hw0 = hwt * 64;
    __shared__ float t[32][65];
    int tx = threadIdx.x;
    int col = tx & 63, r4 = tx >> 6;
#pragma unroll
    for (int rr = 0; rr < 8; ++rr) {
        int row = rr * 4 + r4;
        t[row][col] = x[((size_t)n * CI + ci0 + row) * HWP + hw0 + col];
    }
    __syncthreads();
    int i = tx & 31, j0 = tx >> 5;
#pragma unroll
    for (int jj = 0; jj < 8; ++jj) {
        int j = jj * 8 + j0;
        int hw = hw0 + j;
        int h = hw / WW, w = hw % WW;
        xTp[(((size_t)n * HP + h + 1) * WP + (w + 1)) * CI + ci0 + i] = f2bf(t[i][j]);
    }
}

// ---- zero-fill padded borders ----
__global__ __launch_bounds__(256) void xform_border(ushort* __restrict__ xTp) {
    int u = blockIdx.x * 256 + threadIdx.x;   // 116736 units of short8
    int ci8 = u & 15;
    int r = u >> 4;
    int n = r / 228, bb = r % 228;
    int hp, wp;
    if (bb < 58)       { hp = 0;  wp = bb; }
    else if (bb < 116) { hp = 57; wp = bb - 58; }
    else { int c = bb - 116; hp = 1 + (c >> 1); wp = (c & 1) * 57; }
    short8 z = (short8)0;
    *reinterpret_cast<short8*>(xTp + (((size_t)n * HP + hp) * WP + wp) * CI + ci8 * 8) = z;
}

// ---- w: [co][ci][kh][kw] f32 -> wT: [tap][co][ci] bf16 ----
__global__ __launch_bounds__(256) void xform_w(const float* __restrict__ w,
                                               ushort* __restrict__ wT) {
    int o = blockIdx.x * 256 + threadIdx.x;
    int ci = o & 127;
    int co = (o >> 7) & 255;
    int tap = o >> 15;
    wT[o] = f2bf(w[((size_t)co * CI + ci) * 9 + tap]);
}

// ---- main implicit GEMM: 256x256 tile, 1 barrier/tile, pipelined frags ----
__global__ __launch_bounds__(512, 2) void gemm_conv(
    const ushort* __restrict__ xTp, const ushort* __restrict__ wT,
    const float* __restrict__ bias, float* __restrict__ out)
{
    __shared__ ushort As[2][256 * 64];   // 32KB x2 (weights: co x k)
    __shared__ ushort Bs[2][256 * 64];   // 32KB x2 (im2col : m  x k)

    // XCD swizzle: 392 = 8 x 49, bijective
    int b = blockIdx.x;
    const int mblk = (b & 7) * 49 + (b >> 3);

    const int tid = threadIdx.x, lane = tid & 63, wv = tid >> 6;  // 8 waves
    const int wr = wv >> 2;          // co-half  (0..1) -> 128 co rows
    const int wc = wv & 3;           // m-quarter(0..3) -> 64 m cols

    // staging addressing (half-tile = 128 rows x 64 k = 16KB; 2 loads/thr)
    const int s8 = (((tid & 7) ^ ((tid >> 3) & 7))) * 8;   // src chunk elems
    const int aSrc = (tid >> 3) * CI + s8;
    const int dstOff = (tid >> 3) * 64 + (tid & 7) * 8;

    int bPix[4];  // [h*2+q]: pixel base offset incl. s8
#pragma unroll
    for (int hq = 0; hq < 4; ++hq) {
        int m = mblk * 256 + (hq >> 1) * 128 + (hq & 1) * 64 + (tid >> 3);
        int n = m / HWP, hw = m % HWP, h = hw / WW, w = hw % WW;
        bPix[hq] = ((n * HP + h + 1) * WP + (w + 1)) * CI + s8;
    }

    // fragment-read addressing
    const int ck0 = (((lane >> 4)) ^ (lane & 7)) * 8;
    const int ck1 = ((4 + (lane >> 4)) ^ (lane & 7)) * 8;
    const int aRowOff = (wr * 128 + (lane & 15)) * 64;
    const int bRowOff = (wc * 64 + (lane & 15)) * 64;

    float4v acc[8][4];
#pragma unroll
    for (int i = 0; i < 8; ++i)
#pragma unroll
        for (int j = 0; j < 4; ++j) acc[i][j] = (float4v)(0.0f);

    short8 aF[4][2];
    short8 bQ0[2][2];
    short8 bQ1[2][2];

    auto STAGE_A = [&](int buf, int t, int h) {
        int tap = t >> 1, kh = (t & 1) * 64;
        const ushort* src = wT + aSrc + tap * (CO * CI) + kh + h * 16384;
        ushort* dst = &As[buf][h * 8192 + dstOff];
        gll(src, dst);
        gll(src + 8192, dst + 4096);
    };
    auto STAGE_B = [&](int buf, int t, int h) {
        int tap = t >> 1, kh = (t & 1) * 64;
        int dh = tap / 3 - 1, dw = tap % 3 - 1;
        int toff = (dh * WP + dw) * CI + kh;
        ushort* dst = &Bs[buf][h * 8192 + dstOff];
        gll(xTp + bPix[h * 2 + 0] + toff, dst);
        gll(xTp + bPix[h * 2 + 1] + toff, dst + 4096);
    };
    auto STAGE_TILE = [&](int buf, int t) {
        STAGE_A(buf, t, 0); STAGE_A(buf, t, 1);
        STAGE_B(buf, t, 0); STAGE_B(buf, t, 1);
    };
    auto LDA = [&](int buf, int qr) {
        const ushort* p = &As[buf][aRowOff + qr * 4096];
#pragma unroll
        for (int fi = 0; fi < 4; ++fi) {
            aF[fi][0] = *(const short8*)(p + fi * 1024 + ck0);
            aF[fi][1] = *(const short8*)(p + fi * 1024 + ck1);
        }
    };
    auto LDB = [&](int buf, int qc, short8 (&bF)[2][2]) {
        const ushort* p = &Bs[buf][bRowOff + qc * 2048];
#pragma unroll
        for (int gi = 0; gi < 2; ++gi) {
            bF[gi][0] = *(const short8*)(p + gi * 1024 + ck0);
            bF[gi][1] = *(const short8*)(p + gi * 1024 + ck1);
        }
    };

// kc-OUTER: two runs of 8 independent MFMAs
#define MMQ(QR, QC, BF) do { \
    __builtin_amdgcn_s_setprio(1); \
    _Pragma("unroll") \
    for (int kc = 0; kc < 2; ++kc) \
        _Pragma("unroll") \
        for (int fi = 0; fi < 4; ++fi) \
            _Pragma("unroll") \
            for (int gi = 0; gi < 2; ++gi) \
                acc[(QR)*4+fi][(QC)*2+gi] = __builtin_amdgcn_mfma_f32_16x16x32_bf16( \
                    aF[fi][kc], (BF)[gi][kc], acc[(QR)*4+fi][(QC)*2+gi], 0, 0, 0); \
    __builtin_amdgcn_s_setprio(0); \
} while (0)

    // prologue: tile 0 staged; collective land
    STAGE_TILE(0, 0);
    asm volatile("s_waitcnt vmcnt(0)" ::: "memory");
    BAR();

#pragma unroll 1
    for (int t = 0; t < 18; ++t) {
        const int c = t & 1;
        // stage next tile -> other buffer (its last readers retired at the
        // barrier we just passed); full tile of flight time before use.
        if (t + 1 < 18) STAGE_TILE(c ^ 1, t + 1);
        // fragment pipeline on buf c (compiler emits per-register lgkm waits;
        // bQ1 loads stay outstanding under MMQ(0,0); LDA(c,1) issues after
        // MMQ(0,1)'s issue via WAR on aF and completes under its execution).
        LDA(c, 0);
        LDB(c, 0, bQ0);
        LDB(c, 1, bQ1);
        MMQ(0, 0, bQ0);
        MMQ(0, 1, bQ1);
        LDA(c, 1);
        MMQ(1, 1, bQ1);
        MMQ(1, 0, bQ0);
        // boundary: this tile's staged loads (for t+1) have had a full tile
        // to land -> vmcnt(0) ~free; barrier makes it collective.
        asm volatile("s_waitcnt vmcnt(0)" ::: "memory");
        BAR();
    }
#undef MMQ

    // epilogue (R7 scalar form): C[co][m] + bias -> out[n][co][h][w]
    const int co0 = wr * 128;
    const int m0  = mblk * 256 + wc * 64;
    float bv[8][4];
#pragma unroll
    for (int f = 0; f < 8; ++f)
#pragma unroll
        for (int r = 0; r < 4; ++r)
            bv[f][r] = bias[co0 + f * 16 + (lane >> 4) * 4 + r];
#pragma unroll
    for (int g = 0; g < 4; ++g) {
        int m = m0 + g * 16 + (lane & 15);
        int n = m / HWP, hw = m % HWP;
        float* obase = out + (size_t)n * CO * HWP + hw;
#pragma unroll
        for (int f = 0; f < 8; ++f) {
            int co = co0 + f * 16 + (lane >> 4) * 4;
#pragma unroll
            for (int r = 0; r < 4; ++r)
                obase[(size_t)(co + r) * HWP] = acc[f][g][r] + bv[f][r];
        }
    }
}

// ---- fallback (round-1 direct conv) if ws too small ----
__global__ __launch_bounds__(256) void conv_k(
    const float* __restrict__ x, const float* __restrict__ wgt,
    const float* __restrict__ bias, float* __restrict__ out)
{
    int idx = blockIdx.x * 256 + threadIdx.x;
    int wg = idx % 14; int t = idx / 14;
    int ho = t % 56; t /= 56;
    int cog = t % 64; int n = t / 64;
    int w0 = wg * 4, co0 = cog * 4;
    float acc[4][4];
#pragma unroll
    for (int j = 0; j < 4; ++j) {
        float bj = bias[co0 + j];
#pragma unroll
        for (int p = 0; p < 4; ++p) acc[j][p] = bj;
    }
    const float* xn = x + (size_t)n * CI * HWP;
    for (int ci = 0; ci < CI; ++ci) {
        float xr[3][6];
#pragma unroll
        for (int kh = 0; kh < 3; ++kh) {
            int hi = ho + kh - 1;
            if (hi >= 0 && hi < HH) {
                const float* row = xn + ((size_t)ci * HH + hi) * WW;
                float4 cc = *reinterpret_cast<const float4*>(row + w0);
                xr[kh][1] = cc.x; xr[kh][2] = cc.y; xr[kh][3] = cc.z; xr[kh][4] = cc.w;
                xr[kh][0] = (w0 > 0) ? row[w0 - 1] : 0.0f;
                xr[kh][5] = (w0 + 4 < WW) ? row[w0 + 4] : 0.0f;
            } else {
#pragma unroll
                for (int q = 0; q < 6; ++q) xr[kh][q] = 0.0f;
            }
        }
#pragma unroll
        for (int j = 0; j < 4; ++j) {
            const float* wp = wgt + ((size_t)(co0 + j) * CI + ci) * 9;
            float wvv[9];
#pragma unroll
            for (int q = 0; q < 9; ++q) wvv[q] = wp[q];
#pragma unroll
            for (int kh = 0; kh < 3; ++kh)
#pragma unroll
                for (int kw = 0; kw < 3; ++kw)
#pragma unroll
                    for (int p = 0; p < 4; ++p)
                        acc[j][p] = fmaf(xr[kh][p + kw], wvv[kh * 3 + kw], acc[j][p]);
        }
    }
#pragma unroll
    for (int j = 0; j < 4; ++j) {
        float4 v = make_float4(acc[j][0], acc[j][1], acc[j][2], acc[j][3]);
        *reinterpret_cast<float4*>(out + (((size_t)n * CO + co0 + j) * HH + ho) * WW + w0) = v;
    }
}

extern "C" void kernel_launch(void* const* d_in, const int* in_sizes, int n_in,
                              void* d_out, int out_size, void* d_ws, size_t ws_size,
                              hipStream_t stream) {
    const float* x = (const float*)d_in[0];
    const float* w = (const float*)d_in[1];
    const float* b = (const float*)d_in[2];
    float* out = (float*)d_out;

    if (ws_size < WS_NEED) {  // safety fallback
        hipLaunchKernelGGL(conv_k, dim3(6272), dim3(256), 0, stream, x, w, b, out);
        return;
    }

    ushort* xTp = (ushort*)d_ws;
    ushort* wT  = (ushort*)((char*)d_ws + WT_OFF);

    hipLaunchKernelGGL(xform_x, dim3(32 * 49 * 4), dim3(256), 0, stream, x, xTp);
    hipLaunchKernelGGL(xform_border, dim3(456), dim3(256), 0, stream, xTp);
    hipLaunchKernelGGL(xform_w, dim3(9 * CO * CI / 256), dim3(256), 0, stream, w, wT);
    hipLaunchKernelGGL(gemm_conv, dim3(392), dim3(512), 0, stream,
                       xTp, wT, b, out);
}

// Round 10
// 103.260 us; speedup vs baseline: 1.4422x; 1.0126x over previous
//
#include <hip/hip_runtime.h>

// Conv2d 3x3 s1 p1 NCHW fp32: N=32, Cin=128, H=W=56, Cout=256.
// Round 10: SMALL-BLOCK / HIGH-TLP implicit GEMM (m97 regime).
//   Block: 256 thr (4 waves), tile 64co x 128m, BK=64, wave-tile 32x64.
//   LDS 48KB dbuf + ~120 VGPR (__launch_bounds__(256,3)) -> 3 blocks/CU:
//   cross-block TLP hides barrier drains (m97's mechanism, 912 TF evidence).
//   Grid 3136 = 784m x 4co -> busiest CU 13 vs avg 12.25 = 94.2% tail
//   (vs 392-block config's 76.6%). XCD swizzle: co fastest (B-tile L2 reuse),
//   m contiguous per XCD (3.3MB xTp slice fits 4MB L2).
//   Simple 2-barrier dbuf loop; staging XOR-swizzle (^row&7) as verified
//   R2-R9 (0 conflicts). Scalar epilogue (R8 vector epilogue: 3.25x write amp).

typedef __attribute__((ext_vector_type(8))) short short8;
typedef __attribute__((ext_vector_type(4))) float float4v;

constexpr int NB = 32, CI = 128, HH = 56, WW = 56, CO = 256;
constexpr int HWP = HH * WW;                 // 3136
constexpr int HP = 58, WP = 58;              // padded spatial dims
constexpr size_t XTP_BYTES = (size_t)NB * HP * WP * CI * 2;   // 27,553,792
constexpr size_t WT_OFF    = XTP_BYTES;
constexpr size_t WT_BYTES  = (size_t)9 * CO * CI * 2;         // 589,824
constexpr size_t WS_NEED   = WT_OFF + WT_BYTES;

__device__ inline ushort f2bf(float v) {
    union { float f; uint u; } c; c.f = v;
    uint u = c.u;
    return (ushort)((u + 0x7fffu + ((u >> 16) & 1u)) >> 16);
}

__device__ inline void gll(const ushort* g, ushort* l) {
    __builtin_amdgcn_global_load_lds(
        (const __attribute__((address_space(1))) uint*)g,
        (__attribute__((address_space(3))) uint*)l, 16, 0, 0);
}

// ---- x: [n][ci][h][w] f32 -> xTp interior: [n][h+1][w+1][ci] bf16 ----
__global__ __launch_bounds__(256) void xform_x(const float* __restrict__ x,
                                               ushort* __restrict__ xTp) {
    int b = blockIdx.x;
    int cit = b & 3;
    int hwt = (b >> 2) % 49;
    int n   = b / (4 * 49);
    int ci0 = cit * 32, hw0 = hwt * 64;
    __shared__ float t[32][65];
    int tx = threadIdx.x;
    int col = tx & 63, r4 = tx >> 6;
#pragma unroll
    for (int rr = 0; rr < 8; ++rr) {
        int row = rr * 4 + r4;
        t[row][col] = x[((size_t)n * CI + ci0 + row) * HWP + hw0 + col];
    }
    __syncthreads();
    int i = tx & 31, j0 = tx >> 5;
#pragma unroll
    for (int jj = 0; jj < 8; ++jj) {
        int j = jj * 8 + j0;
        int hw = hw0 + j;
        int h = hw / WW, w = hw % WW;
        xTp[(((size_t)n * HP + h + 1) * WP + (w + 1)) * CI + ci0 + i] = f2bf(t[i][j]);
    }
}

// ---- zero-fill padded borders ----
__global__ __launch_bounds__(256) void xform_border(ushort* __restrict__ xTp) {
    int u = blockIdx.x * 256 + threadIdx.x;   // 116736 units of short8
    int ci8 = u & 15;
    int r = u >> 4;
    int n = r / 228, bb = r % 228;
    int hp, wp;
    if (bb < 58)       { hp = 0;  wp = bb; }
    else if (bb < 116) { hp = 57; wp = bb - 58; }
    else { int c = bb - 116; hp = 1 + (c >> 1); wp = (c & 1) * 57; }
    short8 z = (short8)0;
    *reinterpret_cast<short8*>(xTp + (((size_t)n * HP + hp) * WP + wp) * CI + ci8 * 8) = z;
}

// ---- w: [co][ci][kh][kw] f32 -> wT: [tap][co][ci] bf16 ----
__global__ __launch_bounds__(256) void xform_w(const float* __restrict__ w,
                                               ushort* __restrict__ wT) {
    int o = blockIdx.x * 256 + threadIdx.x;
    int ci = o & 127;
    int co = (o >> 7) & 255;
    int tap = o >> 15;
    wT[o] = f2bf(w[((size_t)co * CI + ci) * 9 + tap]);
}

// ---- main implicit GEMM: 64co x 128m blocks, 4 waves, 3 blocks/CU ----
__global__ __launch_bounds__(256, 3) void gemm_conv(
    const ushort* __restrict__ xTp, const ushort* __restrict__ wT,
    const float* __restrict__ bias, float* __restrict__ out)
{
    __shared__ ushort As[2][64 * 64];    //  8KB x2 (weights: 64co x 64k)
    __shared__ ushort Bs[2][128 * 64];   // 16KB x2 (im2col : 128m x 64k)

    // XCD swizzle: 3136 = 8 x 392; co fastest (B L2 reuse), m contiguous/XCD
    int b = blockIdx.x;
    int logical = (b & 7) * 392 + (b >> 3);
    const int cblk = logical & 3;        // 0..3 (64 co each)
    const int mblk = logical >> 2;       // 0..783 (128 m each)

    const int tid = threadIdx.x, lane = tid & 63, wv = tid >> 6;  // 4 waves
    const int wr = wv >> 1;              // co-half (0..1) -> 32 co
    const int wc = wv & 1;               // m-half  (0..1) -> 64 m

    // ---- staging addressing: 8 threads per 128B row; 2 A-passes, 4 B-passes
    const int s8 = (((tid & 7) ^ ((tid >> 3) & 7))) * 8;   // src chunk elems
    const int rowL = tid >> 3;                              // 0..31
    const int dstB = rowL * 64 + (tid & 7) * 8;             // + pass*2048

    int aOff[2];
#pragma unroll
    for (int p = 0; p < 2; ++p)
        aOff[p] = (cblk * 64 + p * 32 + rowL) * CI + s8;    // + tap*CO*CI + kh
    int bPix[4];
#pragma unroll
    for (int p = 0; p < 4; ++p) {
        int m = mblk * 128 + p * 32 + rowL;
        int n = m / HWP, hw = m % HWP, h = hw / WW, w = hw % WW;
        bPix[p] = ((n * HP + h + 1) * WP + (w + 1)) * CI + s8;  // + tapoff + kh
    }

    // ---- fragment-read addressing (same verified pattern)
    const int ck0 = (((lane >> 4)) ^ (lane & 7)) * 8;
    const int ck1 = ((4 + (lane >> 4)) ^ (lane & 7)) * 8;
    const int aRowOff = (wr * 32 + (lane & 15)) * 64;       // + fi*1024
    const int bRowOff = (wc * 64 + (lane & 15)) * 64;       // + gi*1024

    float4v acc[2][4];
#pragma unroll
    for (int i = 0; i < 2; ++i)
#pragma unroll
        for (int j = 0; j < 4; ++j) acc[i][j] = (float4v)(0.0f);

    auto STAGE = [&](int buf, int t) {
        int tap = t >> 1, kh = (t & 1) * 64;
        int ao = tap * (CO * CI) + kh;
        ushort* asb = &As[buf][0];
#pragma unroll
        for (int p = 0; p < 2; ++p)
            gll(wT + aOff[p] + ao, asb + p * 2048 + dstB);
        int dh = tap / 3 - 1, dw = tap % 3 - 1;
        int bo = (dh * WP + dw) * CI + kh;
        ushort* bsb = &Bs[buf][0];
#pragma unroll
        for (int p = 0; p < 4; ++p)
            gll(xTp + bPix[p] + bo, bsb + p * 2048 + dstB);
    };

    auto COMPUTE = [&](int buf) {
        const ushort* asb = &As[buf][0];
        const ushort* bsb = &Bs[buf][0];
        short8 aF[2][2], bF[4][2];
#pragma unroll
        for (int fi = 0; fi < 2; ++fi) {
            aF[fi][0] = *(const short8*)(asb + aRowOff + fi * 1024 + ck0);
            aF[fi][1] = *(const short8*)(asb + aRowOff + fi * 1024 + ck1);
        }
#pragma unroll
        for (int gi = 0; gi < 4; ++gi) {
            bF[gi][0] = *(const short8*)(bsb + bRowOff + gi * 1024 + ck0);
            bF[gi][1] = *(const short8*)(bsb + bRowOff + gi * 1024 + ck1);
        }
        __builtin_amdgcn_s_setprio(1);
#pragma unroll
        for (int kc = 0; kc < 2; ++kc)
#pragma unroll
            for (int fi = 0; fi < 2; ++fi)
#pragma unroll
                for (int gi = 0; gi < 4; ++gi)
                    acc[fi][gi] = __builtin_amdgcn_mfma_f32_16x16x32_bf16(
                        aF[fi][kc], bF[gi][kc], acc[fi][gi], 0, 0, 0);
        __builtin_amdgcn_s_setprio(0);
    };

    // m97-style 2-barrier double-buffered loop (TLP hides the drains)
    STAGE(0, 0);
    __syncthreads();
#pragma unroll 1
    for (int t = 0; t < 18; ++t) {
        const int cur = t & 1;
        if (t + 1 < 18) STAGE(cur ^ 1, t + 1);
        COMPUTE(cur);
        __syncthreads();
    }

    // epilogue: C[co][m] + bias -> out[n][co][h][w] (scalar form, 1.2x amp)
    const int co0 = cblk * 64 + wr * 32;
    const int m0  = mblk * 128 + wc * 64;
    float bv[2][4];
#pragma unroll
    for (int f = 0; f < 2; ++f)
#pragma unroll
        for (int r = 0; r < 4; ++r)
            bv[f][r] = bias[co0 + f * 16 + (lane >> 4) * 4 + r];
#pragma unroll
    for (int g = 0; g < 4; ++g) {
        int m = m0 + g * 16 + (lane & 15);
        int n = m / HWP, hw = m % HWP;
        float* obase = out + (size_t)n * CO * HWP + hw;
#pragma unroll
        for (int f = 0; f < 2; ++f) {
            int co = co0 + f * 16 + (lane >> 4) * 4;
#pragma unroll
            for (int r = 0; r < 4; ++r)
                obase[(size_t)(co + r) * HWP] = acc[f][g][r] + bv[f][r];
        }
    }
}

// ---- fallback (round-1 direct conv) if ws too small ----
__global__ __launch_bounds__(256) void conv_k(
    const float* __restrict__ x, const float* __restrict__ wgt,
    const float* __restrict__ bias, float* __restrict__ out)
{
    int idx = blockIdx.x * 256 + threadIdx.x;
    int wg = idx % 14; int t = idx / 14;
    int ho = t % 56; t /= 56;
    int cog = t % 64; int n = t / 64;
    int w0 = wg * 4, co0 = cog * 4;
    float acc[4][4];
#pragma unroll
    for (int j = 0; j < 4; ++j) {
        float bj = bias[co0 + j];
#pragma unroll
        for (int p = 0; p < 4; ++p) acc[j][p] = bj;
    }
    const float* xn = x + (size_t)n * CI * HWP;
    for (int ci = 0; ci < CI; ++ci) {
        float xr[3][6];
#pragma unroll
        for (int kh = 0; kh < 3; ++kh) {
            int hi = ho + kh - 1;
            if (hi >= 0 && hi < HH) {
                const float* row = xn + ((size_t)ci * HH + hi) * WW;
                float4 cc = *reinterpret_cast<const float4*>(row + w0);
                xr[kh][1] = cc.x; xr[kh][2] = cc.y; xr[kh][3] = cc.z; xr[kh][4] = cc.w;
                xr[kh][0] = (w0 > 0) ? row[w0 - 1] : 0.0f;
                xr[kh][5] = (w0 + 4 < WW) ? row[w0 + 4] : 0.0f;
            } else {
#pragma unroll
                for (int q = 0; q < 6; ++q) xr[kh][q] = 0.0f;
            }
        }
#pragma unroll
        for (int j = 0; j < 4; ++j) {
            const float* wp = wgt + ((size_t)(co0 + j) * CI + ci) * 9;
            float wvv[9];
#pragma unroll
            for (int q = 0; q < 9; ++q) wvv[q] = wp[q];
#pragma unroll
            for (int kh = 0; kh < 3; ++kh)
#pragma unroll
                for (int kw = 0; kw < 3; ++kw)
#pragma unroll
                    for (int p = 0; p < 4; ++p)
                        acc[j][p] = fmaf(xr[kh][p + kw], wvv[kh * 3 + kw], acc[j][p]);
        }
    }
#pragma unroll
    for (int j = 0; j < 4; ++j) {
        float4 v = make_float4(acc[j][0], acc[j][1], acc[j][2], acc[j][3]);
        *reinterpret_cast<float4*>(out + (((size_t)n * CO + co0 + j) * HH + ho) * WW + w0) = v;
    }
}

extern "C" void kernel_launch(void* const* d_in, const int* in_sizes, int n_in,
                              void* d_out, int out_size, void* d_ws, size_t ws_size,
                              hipStream_t stream) {
    const float* x = (const float*)d_in[0];
    const float* w = (const float*)d_in[1];
    const float* b = (const float*)d_in[2];
    float* out = (float*)d_out;

    if (ws_size < WS_NEED) {  // safety fallback
        hipLaunchKernelGGL(conv_k, dim3(6272), dim3(256), 0, stream, x, w, b, out);
        return;
    }

    ushort* xTp = (ushort*)d_ws;
    ushort* wT  = (ushort*)((char*)d_ws + WT_OFF);

    hipLaunchKernelGGL(xform_x, dim3(32 * 49 * 4), dim3(256), 0, stream, x, xTp);
    hipLaunchKernelGGL(xform_border, dim3(456), dim3(256), 0, stream, xTp);
    hipLaunchKernelGGL(xform_w, dim3(9 * CO * CI / 256), dim3(256), 0, stream, w, wT);
    hipLaunchKernelGGL(gemm_conv, dim3(3136), dim3(256), 0, stream,
                       xTp, wT, b, out);
}